// Round 2
// baseline (564.118 us; speedup 1.0000x reference)
//
#include <hip/hip_runtime.h>
#include <hip/hip_bf16.h>

#define T_TOK 4096
#define H_DIM 768
#define E_NUM 8
#define F_DIM 1536

typedef __bf16 bf16x8 __attribute__((ext_vector_type(8)));
typedef float f32x4 __attribute__((ext_vector_type(4)));
typedef unsigned int u32;

__device__ __forceinline__ unsigned short f2bf(float f) {
    unsigned int u = __float_as_uint(f);
    u += 0x7FFF + ((u >> 16) & 1);   // RNE
    return (unsigned short)(u >> 16);
}

// async global(16B/lane) -> LDS (wave-uniform base + lane*16)
__device__ __forceinline__ void gload16(const unsigned short* g, unsigned short* l) {
    __builtin_amdgcn_global_load_lds(
        (const __attribute__((address_space(1))) u32*)(g),
        (__attribute__((address_space(3))) u32*)(l),
        16, 0, 0);
}

// ---------------- fp32 -> bf16 convert ----------------
__global__ void convert_bf16_kernel(const float* __restrict__ src,
                                    unsigned short* __restrict__ dst, int n) {
    int i = (blockIdx.x * blockDim.x + threadIdx.x) * 4;
    int stride = gridDim.x * blockDim.x * 4;
    for (; i < n; i += stride) {
        float4 v = *reinterpret_cast<const float4*>(src + i);
        ushort4 o;
        o.x = f2bf(v.x); o.y = f2bf(v.y); o.z = f2bf(v.z); o.w = f2bf(v.w);
        *reinterpret_cast<ushort4*>(dst + i) = o;
    }
}

// ---------------- router: logits + top2 + lists ----------------
__global__ void router_kernel(const float* __restrict__ x,
                              const float* __restrict__ gw,
                              float* __restrict__ logits_out,
                              float* __restrict__ weight,
                              int* __restrict__ list,
                              int* __restrict__ counts) {
    int t = blockIdx.x;
    int lane = threadIdx.x;
    const float* xr = x + (size_t)t * H_DIM;
    float xv[12];
#pragma unroll
    for (int i = 0; i < 12; ++i) xv[i] = xr[lane + i * 64];
    float lg[E_NUM];
#pragma unroll
    for (int e = 0; e < E_NUM; ++e) {
        const float* g = gw + e * H_DIM;
        float p = 0.f;
#pragma unroll
        for (int i = 0; i < 12; ++i) p += xv[i] * g[lane + i * 64];
#pragma unroll
        for (int off = 32; off > 0; off >>= 1) p += __shfl_xor(p, off);
        lg[e] = p;
    }
    if (lane == 0) {
#pragma unroll
        for (int e = 0; e < E_NUM; ++e) logits_out[t * E_NUM + e] = lg[e];
        int e0 = 0; float m0 = lg[0];
#pragma unroll
        for (int e = 1; e < E_NUM; ++e) if (lg[e] > m0) { m0 = lg[e]; e0 = e; }
        int e1 = -1; float m1 = -1e30f;
#pragma unroll
        for (int e = 0; e < E_NUM; ++e) {
            if (e == e0) continue;
            if (lg[e] > m1) { m1 = lg[e]; e1 = e; }
        }
        float z1 = __expf(m1 - m0);
        float w0 = 1.f / (1.f + z1);
        weight[t * 2 + 0] = w0;
        weight[t * 2 + 1] = 1.f - w0;
        int p0 = atomicAdd(&counts[e0], 1);
        list[e0 * T_TOK + p0] = t * 2;
        int p1 = atomicAdd(&counts[e1], 1);
        list[e1 * T_TOK + p1] = t * 2 + 1;
    }
}

// ---------------- GEMM 1&3 fused: act = silu(X w1^T) * (X w3^T) ----------------
// 128x128 tile, 4 waves (2x2), BK=32, global_load_lds staging.
__global__ __launch_bounds__(256) void gemm13_kernel(
    const unsigned short* __restrict__ xb,
    const unsigned short* __restrict__ w1b,
    const unsigned short* __restrict__ w3b,
    const int* __restrict__ list,
    const int* __restrict__ counts,
    unsigned short* __restrict__ act) {
    int e = blockIdx.z;
    int cnt = counts[e];
    int tm = blockIdx.x;
    if (tm * 128 >= cnt) return;
    int tn = blockIdx.y;
    const int* lst = list + e * T_TOK + tm * 128;
    int mrem = cnt - tm * 128;

    __shared__ unsigned short sA[128 * 32];
    __shared__ unsigned short sB1[128 * 32];
    __shared__ unsigned short sB3[128 * 32];

    int tid = threadIdx.x;
    int lane = tid & 63;
    int wid = tid >> 6;

    // staging: thread tid covers rows r0=tid>>2 (call0) and r0+64 (call1), 16B chunk (tid&3)
    int r0 = tid >> 2;
    int r1 = r0 + 64;
    int c8 = (tid & 3) * 8;   // ushort offset within 32-wide row
    int tok0 = lst[(r0 < mrem) ? r0 : 0] >> 1;
    int tok1 = lst[(r1 < mrem) ? r1 : 0] >> 1;
    const unsigned short* gA0 = xb + (size_t)tok0 * H_DIM + c8;
    const unsigned short* gA1 = xb + (size_t)tok1 * H_DIM + c8;
    const unsigned short* gB1a = w1b + ((size_t)e * F_DIM + tn * 128 + r0) * H_DIM + c8;
    const unsigned short* gB1b = gB1a + (size_t)64 * H_DIM;
    const unsigned short* gB3a = w3b + ((size_t)e * F_DIM + tn * 128 + r0) * H_DIM + c8;
    const unsigned short* gB3b = gB3a + (size_t)64 * H_DIM;

    // wave-uniform LDS bases (1KB per wave per call)
    unsigned short* lA0 = &sA[wid * 512];
    unsigned short* lA1 = &sA[2048 + wid * 512];
    unsigned short* lB1a = &sB1[wid * 512];
    unsigned short* lB1b = &sB1[2048 + wid * 512];
    unsigned short* lB3a = &sB3[wid * 512];
    unsigned short* lB3b = &sB3[2048 + wid * 512];

    int wr = (wid >> 1) * 64;   // wave row origin
    int wc = (wid & 1) * 64;    // wave col origin
    int fr = lane & 15;
    int kb = (lane >> 4) * 8;

    f32x4 accG[4][4] = {};
    f32x4 accU[4][4] = {};

    for (int kt = 0; kt < H_DIM; kt += 32) {
        gload16(gA0 + kt, lA0);
        gload16(gA1 + kt, lA1);
        gload16(gB1a + kt, lB1a);
        gload16(gB1b + kt, lB1b);
        gload16(gB3a + kt, lB3a);
        gload16(gB3b + kt, lB3b);
        __syncthreads();

        bf16x8 a[4], b1[4], b3[4];
#pragma unroll
        for (int mi = 0; mi < 4; ++mi)
            a[mi] = *reinterpret_cast<const bf16x8*>(&sA[(wr + mi * 16 + fr) * 32 + kb]);
#pragma unroll
        for (int ni = 0; ni < 4; ++ni) {
            b1[ni] = *reinterpret_cast<const bf16x8*>(&sB1[(wc + ni * 16 + fr) * 32 + kb]);
            b3[ni] = *reinterpret_cast<const bf16x8*>(&sB3[(wc + ni * 16 + fr) * 32 + kb]);
        }
#pragma unroll
        for (int mi = 0; mi < 4; ++mi)
#pragma unroll
            for (int ni = 0; ni < 4; ++ni) {
                accG[mi][ni] = __builtin_amdgcn_mfma_f32_16x16x32_bf16(a[mi], b1[ni], accG[mi][ni], 0, 0, 0);
                accU[mi][ni] = __builtin_amdgcn_mfma_f32_16x16x32_bf16(a[mi], b3[ni], accU[mi][ni], 0, 0, 0);
            }
        __syncthreads();
    }

    int rg = (lane >> 4) * 4;
    int ci = lane & 15;
#pragma unroll
    for (int mi = 0; mi < 4; ++mi) {
#pragma unroll
        for (int r = 0; r < 4; ++r) {
            int m = wr + mi * 16 + rg + r;
            if (m >= mrem) continue;
            int entry = lst[m];
            size_t rowOff = (size_t)entry * F_DIM + tn * 128;
#pragma unroll
            for (int ni = 0; ni < 4; ++ni) {
                float g = accG[mi][ni][r];
                float u = accU[mi][ni][r];
                float s = g / (1.f + __expf(-g));
                act[rowOff + wc + ni * 16 + ci] = f2bf(s * u);
            }
        }
    }
}

// ---------------- GEMM 2: ybuf = (act w2^T) * route_weight ----------------
__global__ __launch_bounds__(256) void gemm2_kernel(
    const unsigned short* __restrict__ act,
    const unsigned short* __restrict__ w2b,
    const int* __restrict__ list,
    const int* __restrict__ counts,
    const float* __restrict__ weight,
    float* __restrict__ ybuf) {
    int e = blockIdx.z;
    int cnt = counts[e];
    int tm = blockIdx.x;
    if (tm * 128 >= cnt) return;
    int tn = blockIdx.y;
    const int* lst = list + e * T_TOK + tm * 128;
    int mrem = cnt - tm * 128;

    __shared__ unsigned short sA[128 * 32];
    __shared__ unsigned short sB[128 * 32];

    int tid = threadIdx.x;
    int lane = tid & 63;
    int wid = tid >> 6;

    int r0 = tid >> 2;
    int r1 = r0 + 64;
    int c8 = (tid & 3) * 8;
    int row0 = lst[(r0 < mrem) ? r0 : 0];
    int row1 = lst[(r1 < mrem) ? r1 : 0];
    const unsigned short* gA0 = act + (size_t)row0 * F_DIM + c8;
    const unsigned short* gA1 = act + (size_t)row1 * F_DIM + c8;
    const unsigned short* gB0 = w2b + ((size_t)e * H_DIM + tn * 128 + r0) * F_DIM + c8;
    const unsigned short* gB1 = gB0 + (size_t)64 * F_DIM;

    unsigned short* lA0 = &sA[wid * 512];
    unsigned short* lA1 = &sA[2048 + wid * 512];
    unsigned short* lB0 = &sB[wid * 512];
    unsigned short* lB1 = &sB[2048 + wid * 512];

    int wr = (wid >> 1) * 64;
    int wc = (wid & 1) * 64;
    int fr = lane & 15;
    int kb = (lane >> 4) * 8;

    f32x4 acc[4][4] = {};

    for (int kt = 0; kt < F_DIM; kt += 32) {
        gload16(gA0 + kt, lA0);
        gload16(gA1 + kt, lA1);
        gload16(gB0 + kt, lB0);
        gload16(gB1 + kt, lB1);
        __syncthreads();

        bf16x8 a[4], b[4];
#pragma unroll
        for (int mi = 0; mi < 4; ++mi)
            a[mi] = *reinterpret_cast<const bf16x8*>(&sA[(wr + mi * 16 + fr) * 32 + kb]);
#pragma unroll
        for (int ni = 0; ni < 4; ++ni)
            b[ni] = *reinterpret_cast<const bf16x8*>(&sB[(wc + ni * 16 + fr) * 32 + kb]);
#pragma unroll
        for (int mi = 0; mi < 4; ++mi)
#pragma unroll
            for (int ni = 0; ni < 4; ++ni)
                acc[mi][ni] = __builtin_amdgcn_mfma_f32_16x16x32_bf16(a[mi], b[ni], acc[mi][ni], 0, 0, 0);
        __syncthreads();
    }

    int rg = (lane >> 4) * 4;
    int ci = lane & 15;
#pragma unroll
    for (int mi = 0; mi < 4; ++mi) {
#pragma unroll
        for (int r = 0; r < 4; ++r) {
            int m = wr + mi * 16 + rg + r;
            if (m >= mrem) continue;
            int entry = lst[m];
            float wv = weight[entry];
            size_t rowOff = (size_t)entry * H_DIM + tn * 128;
#pragma unroll
            for (int ni = 0; ni < 4; ++ni)
                ybuf[rowOff + wc + ni * 16 + ci] = acc[mi][ni][r] * wv;
        }
    }
}

// ---------------- combine: y[t] = ybuf[2t] + ybuf[2t+1] ----------------
__global__ void combine_kernel(const float* __restrict__ ybuf, float* __restrict__ y) {
    int v = blockIdx.x * blockDim.x + threadIdx.x;
    if (v >= T_TOK * H_DIM / 4) return;
    int t = v / (H_DIM / 4);
    int hv = v % (H_DIM / 4);
    float4 a = reinterpret_cast<const float4*>(ybuf + (size_t)(2 * t) * H_DIM)[hv];
    float4 b = reinterpret_cast<const float4*>(ybuf + (size_t)(2 * t + 1) * H_DIM)[hv];
    float4 r;
    r.x = a.x + b.x; r.y = a.y + b.y; r.z = a.z + b.z; r.w = a.w + b.w;
    reinterpret_cast<float4*>(y)[v] = r;
}

extern "C" void kernel_launch(void* const* d_in, const int* in_sizes, int n_in,
                              void* d_out, int out_size, void* d_ws, size_t ws_size,
                              hipStream_t stream) {
    const float* x  = (const float*)d_in[0];
    const float* gw = (const float*)d_in[1];
    const float* w1 = (const float*)d_in[2];
    const float* w3 = (const float*)d_in[3];
    const float* w2 = (const float*)d_in[4];

    float* y = (float*)d_out;
    float* logits_out = y + (size_t)T_TOK * H_DIM;

    char* ws = (char*)d_ws;
    size_t off = 0;
    auto alloc = [&](size_t bytes) -> char* {
        char* p = ws + off;
        off += (bytes + 255) & ~(size_t)255;
        return p;
    };
    unsigned short* xb  = (unsigned short*)alloc((size_t)T_TOK * H_DIM * 2);
    unsigned short* w1b = (unsigned short*)alloc((size_t)E_NUM * F_DIM * H_DIM * 2);
    unsigned short* w3b = (unsigned short*)alloc((size_t)E_NUM * F_DIM * H_DIM * 2);
    unsigned short* w2b = (unsigned short*)alloc((size_t)E_NUM * H_DIM * F_DIM * 2);
    unsigned short* act = (unsigned short*)alloc((size_t)T_TOK * 2 * F_DIM * 2);
    float* ybuf   = (float*)alloc((size_t)T_TOK * 2 * H_DIM * 4);
    float* weight = (float*)alloc((size_t)T_TOK * 2 * 4);
    int* list     = (int*)alloc((size_t)E_NUM * T_TOK * 4);
    int* counts   = (int*)alloc((size_t)E_NUM * 4);

    hipMemsetAsync(counts, 0, E_NUM * sizeof(int), stream);

    convert_bf16_kernel<<<1024, 256, 0, stream>>>(x, xb, T_TOK * H_DIM);
    convert_bf16_kernel<<<2048, 256, 0, stream>>>(w1, w1b, E_NUM * F_DIM * H_DIM);
    convert_bf16_kernel<<<2048, 256, 0, stream>>>(w3, w3b, E_NUM * F_DIM * H_DIM);
    convert_bf16_kernel<<<2048, 256, 0, stream>>>(w2, w2b, E_NUM * H_DIM * F_DIM);

    router_kernel<<<T_TOK, 64, 0, stream>>>(x, gw, logits_out, weight, list, counts);

    gemm13_kernel<<<dim3(T_TOK / 128, F_DIM / 128, E_NUM), 256, 0, stream>>>(
        xb, w1b, w3b, list, counts, act);

    gemm2_kernel<<<dim3(T_TOK / 128, H_DIM / 128, E_NUM), 256, 0, stream>>>(
        act, w2b, list, counts, weight, ybuf);

    combine_kernel<<<(T_TOK * H_DIM / 4 + 255) / 256, 256, 0, stream>>>(ybuf, y);
}

// Round 3
// 440.551 us; speedup vs baseline: 1.2805x; 1.2805x over previous
//
#include <hip/hip_runtime.h>
#include <hip/hip_bf16.h>

#define T_TOK 4096
#define H_DIM 768
#define E_NUM 8
#define F_DIM 1536

typedef __bf16 bf16x8 __attribute__((ext_vector_type(8)));
typedef float f32x4 __attribute__((ext_vector_type(4)));
typedef unsigned int u32;

__device__ __forceinline__ unsigned short f2bf(float f) {
    unsigned int u = __float_as_uint(f);
    u += 0x7FFF + ((u >> 16) & 1);   // RNE
    return (unsigned short)(u >> 16);
}

// async global(16B/lane) -> LDS (wave-uniform base + lane*16)
__device__ __forceinline__ void gload16(const unsigned short* g, unsigned short* l) {
    __builtin_amdgcn_global_load_lds(
        (const __attribute__((address_space(1))) u32*)(g),
        (__attribute__((address_space(3))) u32*)(l),
        16, 0, 0);
}

// ---------------- fp32 -> bf16 convert ----------------
__global__ void convert_bf16_kernel(const float* __restrict__ src,
                                    unsigned short* __restrict__ dst, int n) {
    int i = (blockIdx.x * blockDim.x + threadIdx.x) * 4;
    int stride = gridDim.x * blockDim.x * 4;
    for (; i < n; i += stride) {
        float4 v = *reinterpret_cast<const float4*>(src + i);
        ushort4 o;
        o.x = f2bf(v.x); o.y = f2bf(v.y); o.z = f2bf(v.z); o.w = f2bf(v.w);
        *reinterpret_cast<ushort4*>(dst + i) = o;
    }
}

// ---------------- router: logits + top2 + lists ----------------
__global__ void router_kernel(const float* __restrict__ x,
                              const float* __restrict__ gw,
                              float* __restrict__ logits_out,
                              float* __restrict__ weight,
                              int* __restrict__ list,
                              int* __restrict__ counts) {
    int t = blockIdx.x;
    int lane = threadIdx.x;
    const float* xr = x + (size_t)t * H_DIM;
    float xv[12];
#pragma unroll
    for (int i = 0; i < 12; ++i) xv[i] = xr[lane + i * 64];
    float lg[E_NUM];
#pragma unroll
    for (int e = 0; e < E_NUM; ++e) {
        const float* g = gw + e * H_DIM;
        float p = 0.f;
#pragma unroll
        for (int i = 0; i < 12; ++i) p += xv[i] * g[lane + i * 64];
#pragma unroll
        for (int off = 32; off > 0; off >>= 1) p += __shfl_xor(p, off);
        lg[e] = p;
    }
    if (lane == 0) {
#pragma unroll
        for (int e = 0; e < E_NUM; ++e) logits_out[t * E_NUM + e] = lg[e];
        int e0 = 0; float m0 = lg[0];
#pragma unroll
        for (int e = 1; e < E_NUM; ++e) if (lg[e] > m0) { m0 = lg[e]; e0 = e; }
        int e1 = -1; float m1 = -1e30f;
#pragma unroll
        for (int e = 0; e < E_NUM; ++e) {
            if (e == e0) continue;
            if (lg[e] > m1) { m1 = lg[e]; e1 = e; }
        }
        float z1 = __expf(m1 - m0);
        float w0 = 1.f / (1.f + z1);
        weight[t * 2 + 0] = w0;
        weight[t * 2 + 1] = 1.f - w0;
        int p0 = atomicAdd(&counts[e0], 1);
        list[e0 * T_TOK + p0] = t * 2;
        int p1 = atomicAdd(&counts[e1], 1);
        list[e1 * T_TOK + p1] = t * 2 + 1;
    }
}

// ---------------- GEMM 1&3 fused: act = silu(X w1^T) * (X w3^T) ----------------
// BM=128, BN=64, BK=32, 4 waves (2x2), wave tile 64x32 (dual acc), gload_lds.
__global__ __launch_bounds__(256, 2) void gemm13_kernel(
    const unsigned short* __restrict__ xb,
    const unsigned short* __restrict__ w1b,
    const unsigned short* __restrict__ w3b,
    const int* __restrict__ list,
    const int* __restrict__ counts,
    unsigned short* __restrict__ act) {
    int e = blockIdx.z;
    int cnt = counts[e];
    int tm = blockIdx.x;
    if (tm * 128 >= cnt) return;
    int tn = blockIdx.y;
    const int* lst = list + e * T_TOK + tm * 128;
    int mrem = cnt - tm * 128;

    __shared__ unsigned short sA[128 * 32];   // 8 KB
    __shared__ unsigned short sB1[64 * 32];   // 4 KB
    __shared__ unsigned short sB3[64 * 32];   // 4 KB

    int tid = threadIdx.x;
    int lane = tid & 63;
    int wid = tid >> 6;

    // staging coords: thread covers row tid>>2, 16B chunk (tid&3)
    int r0 = tid >> 2;        // 0..63
    int r1 = r0 + 64;         // 64..127 (A only)
    int c8 = (tid & 3) * 8;
    int tok0 = lst[(r0 < mrem) ? r0 : 0] >> 1;
    int tok1 = lst[(r1 < mrem) ? r1 : 0] >> 1;
    const unsigned short* gA0 = xb + (size_t)tok0 * H_DIM + c8;
    const unsigned short* gA1 = xb + (size_t)tok1 * H_DIM + c8;
    const unsigned short* gB1 = w1b + ((size_t)e * F_DIM + tn * 64 + r0) * H_DIM + c8;
    const unsigned short* gB3 = w3b + ((size_t)e * F_DIM + tn * 64 + r0) * H_DIM + c8;

    // wave-uniform LDS bases (each wave's lanes write 1024B linearly)
    unsigned short* lA0 = &sA[wid * 512];
    unsigned short* lA1 = &sA[2048 + wid * 512];
    unsigned short* lB1 = &sB1[wid * 512];
    unsigned short* lB3 = &sB3[wid * 512];

    int wr = (wid >> 1) * 64;   // wave row origin (0 or 64)
    int wc = (wid & 1) * 32;    // wave col origin (0 or 32)
    int fr = lane & 15;
    int kb = (lane >> 4) * 8;

    f32x4 accG[4][2] = {};
    f32x4 accU[4][2] = {};

    for (int kt = 0; kt < H_DIM; kt += 32) {
        gload16(gA0 + kt, lA0);
        gload16(gA1 + kt, lA1);
        gload16(gB1 + kt, lB1);
        gload16(gB3 + kt, lB3);
        __syncthreads();

        bf16x8 a[4], b1[2], b3[2];
#pragma unroll
        for (int mi = 0; mi < 4; ++mi)
            a[mi] = *reinterpret_cast<const bf16x8*>(&sA[(wr + mi * 16 + fr) * 32 + kb]);
#pragma unroll
        for (int ni = 0; ni < 2; ++ni) {
            b1[ni] = *reinterpret_cast<const bf16x8*>(&sB1[(wc + ni * 16 + fr) * 32 + kb]);
            b3[ni] = *reinterpret_cast<const bf16x8*>(&sB3[(wc + ni * 16 + fr) * 32 + kb]);
        }
#pragma unroll
        for (int mi = 0; mi < 4; ++mi)
#pragma unroll
            for (int ni = 0; ni < 2; ++ni) {
                accG[mi][ni] = __builtin_amdgcn_mfma_f32_16x16x32_bf16(a[mi], b1[ni], accG[mi][ni], 0, 0, 0);
                accU[mi][ni] = __builtin_amdgcn_mfma_f32_16x16x32_bf16(a[mi], b3[ni], accU[mi][ni], 0, 0, 0);
            }
        __syncthreads();
    }

    int rg = (lane >> 4) * 4;
    int ci = lane & 15;
#pragma unroll
    for (int mi = 0; mi < 4; ++mi) {
#pragma unroll
        for (int r = 0; r < 4; ++r) {
            int m = wr + mi * 16 + rg + r;
            if (m >= mrem) continue;
            int entry = lst[m];
            size_t rowOff = (size_t)entry * F_DIM + tn * 64;
#pragma unroll
            for (int ni = 0; ni < 2; ++ni) {
                float g = accG[mi][ni][r];
                float u = accU[mi][ni][r];
                float s = g / (1.f + __expf(-g));
                act[rowOff + wc + ni * 16 + ci] = f2bf(s * u);
            }
        }
    }
}

// ---------------- GEMM 2: ybuf = (act w2^T) * route_weight ----------------
// BM=128, BN=64, BK=32, 4 waves (2x2), wave tile 64x32.
__global__ __launch_bounds__(256, 2) void gemm2_kernel(
    const unsigned short* __restrict__ act,
    const unsigned short* __restrict__ w2b,
    const int* __restrict__ list,
    const int* __restrict__ counts,
    const float* __restrict__ weight,
    float* __restrict__ ybuf) {
    int e = blockIdx.z;
    int cnt = counts[e];
    int tm = blockIdx.x;
    if (tm * 128 >= cnt) return;
    int tn = blockIdx.y;
    const int* lst = list + e * T_TOK + tm * 128;
    int mrem = cnt - tm * 128;

    __shared__ unsigned short sA[128 * 32];   // 8 KB
    __shared__ unsigned short sB[64 * 32];    // 4 KB

    int tid = threadIdx.x;
    int lane = tid & 63;
    int wid = tid >> 6;

    int r0 = tid >> 2;
    int r1 = r0 + 64;
    int c8 = (tid & 3) * 8;
    int row0 = lst[(r0 < mrem) ? r0 : 0];
    int row1 = lst[(r1 < mrem) ? r1 : 0];
    const unsigned short* gA0 = act + (size_t)row0 * F_DIM + c8;
    const unsigned short* gA1 = act + (size_t)row1 * F_DIM + c8;
    const unsigned short* gB = w2b + ((size_t)e * H_DIM + tn * 64 + r0) * F_DIM + c8;

    unsigned short* lA0 = &sA[wid * 512];
    unsigned short* lA1 = &sA[2048 + wid * 512];
    unsigned short* lB = &sB[wid * 512];

    int wr = (wid >> 1) * 64;
    int wc = (wid & 1) * 32;
    int fr = lane & 15;
    int kb = (lane >> 4) * 8;

    f32x4 acc[4][2] = {};

    for (int kt = 0; kt < F_DIM; kt += 32) {
        gload16(gA0 + kt, lA0);
        gload16(gA1 + kt, lA1);
        gload16(gB + kt, lB);
        __syncthreads();

        bf16x8 a[4], b[2];
#pragma unroll
        for (int mi = 0; mi < 4; ++mi)
            a[mi] = *reinterpret_cast<const bf16x8*>(&sA[(wr + mi * 16 + fr) * 32 + kb]);
#pragma unroll
        for (int ni = 0; ni < 2; ++ni)
            b[ni] = *reinterpret_cast<const bf16x8*>(&sB[(wc + ni * 16 + fr) * 32 + kb]);
#pragma unroll
        for (int mi = 0; mi < 4; ++mi)
#pragma unroll
            for (int ni = 0; ni < 2; ++ni)
                acc[mi][ni] = __builtin_amdgcn_mfma_f32_16x16x32_bf16(a[mi], b[ni], acc[mi][ni], 0, 0, 0);
        __syncthreads();
    }

    int rg = (lane >> 4) * 4;
    int ci = lane & 15;
#pragma unroll
    for (int mi = 0; mi < 4; ++mi) {
#pragma unroll
        for (int r = 0; r < 4; ++r) {
            int m = wr + mi * 16 + rg + r;
            if (m >= mrem) continue;
            int entry = lst[m];
            float wv = weight[entry];
            size_t rowOff = (size_t)entry * H_DIM + tn * 64;
#pragma unroll
            for (int ni = 0; ni < 2; ++ni)
                ybuf[rowOff + wc + ni * 16 + ci] = acc[mi][ni][r] * wv;
        }
    }
}

// ---------------- combine: y[t] = ybuf[2t] + ybuf[2t+1] ----------------
__global__ void combine_kernel(const float* __restrict__ ybuf, float* __restrict__ y) {
    int v = blockIdx.x * blockDim.x + threadIdx.x;
    if (v >= T_TOK * H_DIM / 4) return;
    int t = v / (H_DIM / 4);
    int hv = v % (H_DIM / 4);
    float4 a = reinterpret_cast<const float4*>(ybuf + (size_t)(2 * t) * H_DIM)[hv];
    float4 b = reinterpret_cast<const float4*>(ybuf + (size_t)(2 * t + 1) * H_DIM)[hv];
    float4 r;
    r.x = a.x + b.x; r.y = a.y + b.y; r.z = a.z + b.z; r.w = a.w + b.w;
    reinterpret_cast<float4*>(y)[v] = r;
}

extern "C" void kernel_launch(void* const* d_in, const int* in_sizes, int n_in,
                              void* d_out, int out_size, void* d_ws, size_t ws_size,
                              hipStream_t stream) {
    const float* x  = (const float*)d_in[0];
    const float* gw = (const float*)d_in[1];
    const float* w1 = (const float*)d_in[2];
    const float* w3 = (const float*)d_in[3];
    const float* w2 = (const float*)d_in[4];

    float* y = (float*)d_out;
    float* logits_out = y + (size_t)T_TOK * H_DIM;

    char* ws = (char*)d_ws;
    size_t off = 0;
    auto alloc = [&](size_t bytes) -> char* {
        char* p = ws + off;
        off += (bytes + 255) & ~(size_t)255;
        return p;
    };
    unsigned short* xb  = (unsigned short*)alloc((size_t)T_TOK * H_DIM * 2);
    unsigned short* w1b = (unsigned short*)alloc((size_t)E_NUM * F_DIM * H_DIM * 2);
    unsigned short* w3b = (unsigned short*)alloc((size_t)E_NUM * F_DIM * H_DIM * 2);
    unsigned short* w2b = (unsigned short*)alloc((size_t)E_NUM * H_DIM * F_DIM * 2);
    unsigned short* act = (unsigned short*)alloc((size_t)T_TOK * 2 * F_DIM * 2);
    float* ybuf   = (float*)alloc((size_t)T_TOK * 2 * H_DIM * 4);
    float* weight = (float*)alloc((size_t)T_TOK * 2 * 4);
    int* list     = (int*)alloc((size_t)E_NUM * T_TOK * 4);
    int* counts   = (int*)alloc((size_t)E_NUM * 4);

    hipMemsetAsync(counts, 0, E_NUM * sizeof(int), stream);

    convert_bf16_kernel<<<1024, 256, 0, stream>>>(x, xb, T_TOK * H_DIM);
    convert_bf16_kernel<<<2048, 256, 0, stream>>>(w1, w1b, E_NUM * F_DIM * H_DIM);
    convert_bf16_kernel<<<2048, 256, 0, stream>>>(w3, w3b, E_NUM * F_DIM * H_DIM);
    convert_bf16_kernel<<<2048, 256, 0, stream>>>(w2, w2b, E_NUM * H_DIM * F_DIM);

    router_kernel<<<T_TOK, 64, 0, stream>>>(x, gw, logits_out, weight, list, counts);

    gemm13_kernel<<<dim3(T_TOK / 128, F_DIM / 64, E_NUM), 256, 0, stream>>>(
        xb, w1b, w3b, list, counts, act);

    gemm2_kernel<<<dim3(T_TOK / 128, H_DIM / 64, E_NUM), 256, 0, stream>>>(
        act, w2b, list, counts, weight, ybuf);

    combine_kernel<<<(T_TOK * H_DIM / 4 + 255) / 256, 256, 0, stream>>>(ybuf, y);
}

// Round 4
// 268.304 us; speedup vs baseline: 2.1025x; 1.6420x over previous
//
#include <hip/hip_runtime.h>
#include <hip/hip_bf16.h>

#define T_TOK 4096
#define H_DIM 768
#define E_NUM 8
#define F_DIM 1536

typedef __bf16 bf16x8 __attribute__((ext_vector_type(8)));
typedef float f32x4 __attribute__((ext_vector_type(4)));
typedef unsigned int u32;

#define VMCNT(n) asm volatile("s_waitcnt vmcnt(" #n ")" ::: "memory")
#define CFENCE() asm volatile("" ::: "memory")

__device__ __forceinline__ unsigned short f2bf(float f) {
    unsigned int u = __float_as_uint(f);
    u += 0x7FFF + ((u >> 16) & 1);   // RNE
    return (unsigned short)(u >> 16);
}

// async global(16B/lane) -> LDS (wave-uniform base + lane*16)
__device__ __forceinline__ void gload16(const unsigned short* g, unsigned short* l) {
    __builtin_amdgcn_global_load_lds(
        (const __attribute__((address_space(1))) u32*)(g),
        (__attribute__((address_space(3))) u32*)(l),
        16, 0, 0);
}

// ---------------- fp32 -> bf16 convert ----------------
__global__ void convert_bf16_kernel(const float* __restrict__ src,
                                    unsigned short* __restrict__ dst, int n) {
    int i = (blockIdx.x * blockDim.x + threadIdx.x) * 4;
    int stride = gridDim.x * blockDim.x * 4;
    for (; i < n; i += stride) {
        float4 v = *reinterpret_cast<const float4*>(src + i);
        ushort4 o;
        o.x = f2bf(v.x); o.y = f2bf(v.y); o.z = f2bf(v.z); o.w = f2bf(v.w);
        *reinterpret_cast<ushort4*>(dst + i) = o;
    }
}

// ---------------- router: logits + top2 + lists ----------------
__global__ void router_kernel(const float* __restrict__ x,
                              const float* __restrict__ gw,
                              float* __restrict__ logits_out,
                              float* __restrict__ weight,
                              int* __restrict__ list,
                              int* __restrict__ counts) {
    int t = blockIdx.x;
    int lane = threadIdx.x;
    const float* xr = x + (size_t)t * H_DIM;
    float xv[12];
#pragma unroll
    for (int i = 0; i < 12; ++i) xv[i] = xr[lane + i * 64];
    float lg[E_NUM];
#pragma unroll
    for (int e = 0; e < E_NUM; ++e) {
        const float* g = gw + e * H_DIM;
        float p = 0.f;
#pragma unroll
        for (int i = 0; i < 12; ++i) p += xv[i] * g[lane + i * 64];
#pragma unroll
        for (int off = 32; off > 0; off >>= 1) p += __shfl_xor(p, off);
        lg[e] = p;
    }
    if (lane == 0) {
#pragma unroll
        for (int e = 0; e < E_NUM; ++e) logits_out[t * E_NUM + e] = lg[e];
        int e0 = 0; float m0 = lg[0];
#pragma unroll
        for (int e = 1; e < E_NUM; ++e) if (lg[e] > m0) { m0 = lg[e]; e0 = e; }
        int e1 = -1; float m1 = -1e30f;
#pragma unroll
        for (int e = 0; e < E_NUM; ++e) {
            if (e == e0) continue;
            if (lg[e] > m1) { m1 = lg[e]; e1 = e; }
        }
        float z1 = __expf(m1 - m0);
        float w0 = 1.f / (1.f + z1);
        weight[t * 2 + 0] = w0;
        weight[t * 2 + 1] = 1.f - w0;
        int p0 = atomicAdd(&counts[e0], 1);
        list[e0 * T_TOK + p0] = t * 2;
        int p1 = atomicAdd(&counts[e1], 1);
        list[e1 * T_TOK + p1] = t * 2 + 1;
    }
}

// ---------------- GEMM 1&3 fused: act = silu(X w1^T) * (X w3^T) ----------------
// BM=128, BN=64, BK=32, 4 waves, 2-phase dbuf + counted vmcnt, XCD swizzle,
// XOR chunk swizzle on LDS (source-side pre-swizzle, rule #21).
__global__ __launch_bounds__(256, 2) void gemm13_kernel(
    const unsigned short* __restrict__ xb,
    const unsigned short* __restrict__ w1b,
    const unsigned short* __restrict__ w3b,
    const int* __restrict__ list,
    const int* __restrict__ counts,
    unsigned short* __restrict__ act) {
    // flattened grid 6144 = 32 tm x 24 tn x 8 e; chunk 768 = one expert per XCD
    int orig = blockIdx.x;
    int wg = (orig & 7) * 768 + (orig >> 3);
    int tm = wg & 31;
    int tn = (wg >> 5) % 24;
    int e = wg / (32 * 24);

    int cnt = counts[e];
    if (tm * 128 >= cnt) return;
    const int* lst = list + e * T_TOK + tm * 128;
    int mrem = cnt - tm * 128;

    __shared__ unsigned short sA[2][128 * 32];   // 2 x 8 KB
    __shared__ unsigned short sB1[2][64 * 32];   // 2 x 4 KB
    __shared__ unsigned short sB3[2][64 * 32];   // 2 x 4 KB

    int tid = threadIdx.x;
    int lane = tid & 63;
    int wid = tid >> 6;

    int r0 = tid >> 2;                       // 0..63
    int r1 = r0 + 64;                        // A second half
    int c8 = ((tid & 3) ^ (r0 & 3)) * 8;     // pre-swizzled source chunk
    int tok0 = lst[(r0 < mrem) ? r0 : 0] >> 1;
    int tok1 = lst[(r1 < mrem) ? r1 : 0] >> 1;
    const unsigned short* gA0 = xb + (size_t)tok0 * H_DIM + c8;
    const unsigned short* gA1 = xb + (size_t)tok1 * H_DIM + c8;
    const unsigned short* gB1 = w1b + ((size_t)e * F_DIM + tn * 64 + r0) * H_DIM + c8;
    const unsigned short* gB3 = w3b + ((size_t)e * F_DIM + tn * 64 + r0) * H_DIM + c8;

    auto stage = [&](int b, int kt) {
        gload16(gA0 + kt, &sA[b][wid * 512]);
        gload16(gA1 + kt, &sA[b][2048 + wid * 512]);
        gload16(gB1 + kt, &sB1[b][wid * 512]);
        gload16(gB3 + kt, &sB3[b][wid * 512]);
    };

    int wr = (wid >> 1) * 64;
    int wc = (wid & 1) * 32;
    int fr = lane & 15;
    int kb = ((lane >> 4) ^ (lane & 3)) * 8;   // matching read-side XOR

    f32x4 accG[4][2] = {};
    f32x4 accU[4][2] = {};

    stage(0, 0);
    __syncthreads();    // full drain + barrier (prologue)
    int buf = 0;
    for (int kt = 0; kt < H_DIM; kt += 32) {
        if (kt + 32 < H_DIM) {
            stage(buf ^ 1, kt + 32);
            VMCNT(4);           // wait current buffer's 4 loads; next 4 in flight
        } else {
            VMCNT(0);
        }
        __builtin_amdgcn_s_barrier();
        CFENCE();

        bf16x8 a[4], b1[2], b3[2];
#pragma unroll
        for (int mi = 0; mi < 4; ++mi)
            a[mi] = *reinterpret_cast<const bf16x8*>(&sA[buf][(wr + mi * 16 + fr) * 32 + kb]);
#pragma unroll
        for (int ni = 0; ni < 2; ++ni) {
            b1[ni] = *reinterpret_cast<const bf16x8*>(&sB1[buf][(wc + ni * 16 + fr) * 32 + kb]);
            b3[ni] = *reinterpret_cast<const bf16x8*>(&sB3[buf][(wc + ni * 16 + fr) * 32 + kb]);
        }
#pragma unroll
        for (int mi = 0; mi < 4; ++mi)
#pragma unroll
            for (int ni = 0; ni < 2; ++ni) {
                accG[mi][ni] = __builtin_amdgcn_mfma_f32_16x16x32_bf16(a[mi], b1[ni], accG[mi][ni], 0, 0, 0);
                accU[mi][ni] = __builtin_amdgcn_mfma_f32_16x16x32_bf16(a[mi], b3[ni], accU[mi][ni], 0, 0, 0);
            }
        CFENCE();
        __builtin_amdgcn_s_barrier();   // protect buf before next stage overwrites
        buf ^= 1;
    }

    int rg = (lane >> 4) * 4;
    int ci = lane & 15;
#pragma unroll
    for (int mi = 0; mi < 4; ++mi) {
#pragma unroll
        for (int r = 0; r < 4; ++r) {
            int m = wr + mi * 16 + rg + r;
            if (m >= mrem) continue;
            int entry = lst[m];
            size_t rowOff = (size_t)entry * F_DIM + tn * 64;
#pragma unroll
            for (int ni = 0; ni < 2; ++ni) {
                float g = accG[mi][ni][r];
                float u = accU[mi][ni][r];
                float s = g / (1.f + __expf(-g));
                act[rowOff + wc + ni * 16 + ci] = f2bf(s * u);
            }
        }
    }
}

// ---------------- GEMM 2: ybuf = (act w2^T) * route_weight ----------------
__global__ __launch_bounds__(256, 2) void gemm2_kernel(
    const unsigned short* __restrict__ act,
    const unsigned short* __restrict__ w2b,
    const int* __restrict__ list,
    const int* __restrict__ counts,
    const float* __restrict__ weight,
    float* __restrict__ ybuf) {
    // flattened grid 3072 = 32 tm x 12 tn x 8 e; chunk 384 = one expert per XCD
    int orig = blockIdx.x;
    int wg = (orig & 7) * 384 + (orig >> 3);
    int tm = wg & 31;
    int tn = (wg >> 5) % 12;
    int e = wg / (32 * 12);

    int cnt = counts[e];
    if (tm * 128 >= cnt) return;
    const int* lst = list + e * T_TOK + tm * 128;
    int mrem = cnt - tm * 128;

    __shared__ unsigned short sA[2][128 * 32];   // 2 x 8 KB
    __shared__ unsigned short sB[2][64 * 32];    // 2 x 4 KB

    int tid = threadIdx.x;
    int lane = tid & 63;
    int wid = tid >> 6;

    int r0 = tid >> 2;
    int r1 = r0 + 64;
    int c8 = ((tid & 3) ^ (r0 & 3)) * 8;
    int row0 = lst[(r0 < mrem) ? r0 : 0];
    int row1 = lst[(r1 < mrem) ? r1 : 0];
    const unsigned short* gA0 = act + (size_t)row0 * F_DIM + c8;
    const unsigned short* gA1 = act + (size_t)row1 * F_DIM + c8;
    const unsigned short* gB = w2b + ((size_t)e * H_DIM + tn * 64 + r0) * F_DIM + c8;

    auto stage = [&](int b, int kt) {
        gload16(gA0 + kt, &sA[b][wid * 512]);
        gload16(gA1 + kt, &sA[b][2048 + wid * 512]);
        gload16(gB + kt, &sB[b][wid * 512]);
    };

    int wr = (wid >> 1) * 64;
    int wc = (wid & 1) * 32;
    int fr = lane & 15;
    int kb = ((lane >> 4) ^ (lane & 3)) * 8;

    f32x4 acc[4][2] = {};

    stage(0, 0);
    __syncthreads();
    int buf = 0;
    for (int kt = 0; kt < F_DIM; kt += 32) {
        if (kt + 32 < F_DIM) {
            stage(buf ^ 1, kt + 32);
            VMCNT(3);
        } else {
            VMCNT(0);
        }
        __builtin_amdgcn_s_barrier();
        CFENCE();

        bf16x8 a[4], b[2];
#pragma unroll
        for (int mi = 0; mi < 4; ++mi)
            a[mi] = *reinterpret_cast<const bf16x8*>(&sA[buf][(wr + mi * 16 + fr) * 32 + kb]);
#pragma unroll
        for (int ni = 0; ni < 2; ++ni)
            b[ni] = *reinterpret_cast<const bf16x8*>(&sB[buf][(wc + ni * 16 + fr) * 32 + kb]);
#pragma unroll
        for (int mi = 0; mi < 4; ++mi)
#pragma unroll
            for (int ni = 0; ni < 2; ++ni)
                acc[mi][ni] = __builtin_amdgcn_mfma_f32_16x16x32_bf16(a[mi], b[ni], acc[mi][ni], 0, 0, 0);
        CFENCE();
        __builtin_amdgcn_s_barrier();
        buf ^= 1;
    }

    int rg = (lane >> 4) * 4;
    int ci = lane & 15;
#pragma unroll
    for (int mi = 0; mi < 4; ++mi) {
#pragma unroll
        for (int r = 0; r < 4; ++r) {
            int m = wr + mi * 16 + rg + r;
            if (m >= mrem) continue;
            int entry = lst[m];
            float wv = weight[entry];
            size_t rowOff = (size_t)entry * H_DIM + tn * 64;
#pragma unroll
            for (int ni = 0; ni < 2; ++ni)
                ybuf[rowOff + wc + ni * 16 + ci] = acc[mi][ni][r] * wv;
        }
    }
}

// ---------------- combine: y[t] = ybuf[2t] + ybuf[2t+1] ----------------
__global__ void combine_kernel(const float* __restrict__ ybuf, float* __restrict__ y) {
    int v = blockIdx.x * blockDim.x + threadIdx.x;
    if (v >= T_TOK * H_DIM / 4) return;
    int t = v / (H_DIM / 4);
    int hv = v % (H_DIM / 4);
    float4 a = reinterpret_cast<const float4*>(ybuf + (size_t)(2 * t) * H_DIM)[hv];
    float4 b = reinterpret_cast<const float4*>(ybuf + (size_t)(2 * t + 1) * H_DIM)[hv];
    float4 r;
    r.x = a.x + b.x; r.y = a.y + b.y; r.z = a.z + b.z; r.w = a.w + b.w;
    reinterpret_cast<float4*>(y)[v] = r;
}

extern "C" void kernel_launch(void* const* d_in, const int* in_sizes, int n_in,
                              void* d_out, int out_size, void* d_ws, size_t ws_size,
                              hipStream_t stream) {
    const float* x  = (const float*)d_in[0];
    const float* gw = (const float*)d_in[1];
    const float* w1 = (const float*)d_in[2];
    const float* w3 = (const float*)d_in[3];
    const float* w2 = (const float*)d_in[4];

    float* y = (float*)d_out;
    float* logits_out = y + (size_t)T_TOK * H_DIM;

    char* ws = (char*)d_ws;
    size_t off = 0;
    auto alloc = [&](size_t bytes) -> char* {
        char* p = ws + off;
        off += (bytes + 255) & ~(size_t)255;
        return p;
    };
    unsigned short* xb  = (unsigned short*)alloc((size_t)T_TOK * H_DIM * 2);
    unsigned short* w1b = (unsigned short*)alloc((size_t)E_NUM * F_DIM * H_DIM * 2);
    unsigned short* w3b = (unsigned short*)alloc((size_t)E_NUM * F_DIM * H_DIM * 2);
    unsigned short* w2b = (unsigned short*)alloc((size_t)E_NUM * H_DIM * F_DIM * 2);
    unsigned short* act = (unsigned short*)alloc((size_t)T_TOK * 2 * F_DIM * 2);
    float* ybuf   = (float*)alloc((size_t)T_TOK * 2 * H_DIM * 4);
    float* weight = (float*)alloc((size_t)T_TOK * 2 * 4);
    int* list     = (int*)alloc((size_t)E_NUM * T_TOK * 4);
    int* counts   = (int*)alloc((size_t)E_NUM * 4);

    hipMemsetAsync(counts, 0, E_NUM * sizeof(int), stream);

    convert_bf16_kernel<<<1024, 256, 0, stream>>>(x, xb, T_TOK * H_DIM);
    convert_bf16_kernel<<<2048, 256, 0, stream>>>(w1, w1b, E_NUM * F_DIM * H_DIM);
    convert_bf16_kernel<<<2048, 256, 0, stream>>>(w3, w3b, E_NUM * F_DIM * H_DIM);
    convert_bf16_kernel<<<2048, 256, 0, stream>>>(w2, w2b, E_NUM * H_DIM * F_DIM);

    router_kernel<<<T_TOK, 64, 0, stream>>>(x, gw, logits_out, weight, list, counts);

    gemm13_kernel<<<6144, 256, 0, stream>>>(xb, w1b, w3b, list, counts, act);

    gemm2_kernel<<<3072, 256, 0, stream>>>(act, w2b, list, counts, weight, ybuf);

    combine_kernel<<<(T_TOK * H_DIM / 4 + 255) / 256, 256, 0, stream>>>(ybuf, y);
}

// Round 5
// 176.358 us; speedup vs baseline: 3.1987x; 1.5214x over previous
//
#include <hip/hip_runtime.h>
#include <hip/hip_bf16.h>

#define T_TOK 4096
#define H_DIM 768
#define E_NUM 8
#define F_DIM 1536

typedef __bf16 bf16x8 __attribute__((ext_vector_type(8)));
typedef float f32x4 __attribute__((ext_vector_type(4)));
typedef unsigned int u32;

#define VMCNT(n) asm volatile("s_waitcnt vmcnt(" #n ")" ::: "memory")
#define CFENCE() asm volatile("" ::: "memory")

__device__ __forceinline__ unsigned short f2bf(float f) {
    unsigned int u = __float_as_uint(f);
    u += 0x7FFF + ((u >> 16) & 1);   // RNE
    return (unsigned short)(u >> 16);
}

// async global(16B/lane) -> LDS (wave-uniform base + lane*16)
__device__ __forceinline__ void gload16(const unsigned short* g, unsigned short* l) {
    __builtin_amdgcn_global_load_lds(
        (const __attribute__((address_space(1))) u32*)(g),
        (__attribute__((address_space(3))) u32*)(l),
        16, 0, 0);
}

// ---------------- fp32 -> bf16 convert (weights) ----------------
__global__ void convert_bf16_kernel(const float* __restrict__ src,
                                    unsigned short* __restrict__ dst, int n) {
    int i = (blockIdx.x * blockDim.x + threadIdx.x) * 4;
    int stride = gridDim.x * blockDim.x * 4;
    for (; i < n; i += stride) {
        float4 v = *reinterpret_cast<const float4*>(src + i);
        ushort4 o;
        o.x = f2bf(v.x); o.y = f2bf(v.y); o.z = f2bf(v.z); o.w = f2bf(v.w);
        *reinterpret_cast<ushort4*>(dst + i) = o;
    }
}

// ---------------- router: logits + top2 + x->bf16, NO atomics ----------------
// 1 wave per token, 4 waves/block.
__global__ __launch_bounds__(256) void router_kernel(
    const float* __restrict__ x,
    const float* __restrict__ gw,
    float* __restrict__ logits_out,
    float* __restrict__ weight,
    int* __restrict__ eidx,
    unsigned short* __restrict__ xb) {
    int t = blockIdx.x * 4 + (threadIdx.x >> 6);
    int lane = threadIdx.x & 63;

    const float4* xr = reinterpret_cast<const float4*>(x + (size_t)t * H_DIM);
    float4 xv[3];
#pragma unroll
    for (int i = 0; i < 3; ++i) xv[i] = xr[i * 64 + lane];

    // write bf16 x (replaces x convert kernel)
    unsigned short* xbr = xb + (size_t)t * H_DIM;
#pragma unroll
    for (int i = 0; i < 3; ++i) {
        ushort4 o;
        o.x = f2bf(xv[i].x); o.y = f2bf(xv[i].y);
        o.z = f2bf(xv[i].z); o.w = f2bf(xv[i].w);
        *reinterpret_cast<ushort4*>(xbr + (i * 64 + lane) * 4) = o;
    }

    float v[E_NUM];
#pragma unroll
    for (int e = 0; e < E_NUM; ++e) {
        const float4* g = reinterpret_cast<const float4*>(gw + e * H_DIM);
        float p = 0.f;
#pragma unroll
        for (int i = 0; i < 3; ++i) {
            float4 gv = g[i * 64 + lane];
            p += xv[i].x * gv.x + xv[i].y * gv.y + xv[i].z * gv.z + xv[i].w * gv.w;
        }
        v[e] = p;
    }
    // stage 1: reduce within each 8-lane group (bits 0-2)
#pragma unroll
    for (int d = 1; d < 8; d <<= 1)
#pragma unroll
        for (int e = 0; e < E_NUM; ++e) v[e] += __shfl_xor(v[e], d);
    // each lane owns expert (lane&7): static-index selection chain (no scratch)
    int me = lane & 7;
    float le = v[0];
#pragma unroll
    for (int e = 1; e < E_NUM; ++e) le = (me == e) ? v[e] : le;
    // stage 2: reduce across the 8 groups (bits 3-5)
#pragma unroll
    for (int d = 8; d < 64; d <<= 1) le += __shfl_xor(le, d);

    if (lane < 8) logits_out[t * E_NUM + lane] = le;

    // top-2 via ballots (lowest expert index wins ties, matches lax.top_k)
    float m0 = le;
#pragma unroll
    for (int d = 1; d < 8; d <<= 1) m0 = fmaxf(m0, __shfl_xor(m0, d));
    unsigned long long b0 = __ballot(le == m0);
    int e0 = (__ffsll((long long)b0) - 1) & 7;
    float le1 = (me == e0) ? -3.4e38f : le;
    float m1 = le1;
#pragma unroll
    for (int d = 1; d < 8; d <<= 1) m1 = fmaxf(m1, __shfl_xor(m1, d));
    unsigned long long b1 = __ballot(le1 == m1);
    int e1 = (__ffsll((long long)b1) - 1) & 7;

    if (lane == 0) {
        float w0 = 1.f / (1.f + __expf(m1 - m0));
        weight[t * 2 + 0] = w0;
        weight[t * 2 + 1] = 1.f - w0;
        eidx[t] = e0 | (e1 << 8);
    }
}

// ---------------- build per-expert token lists (sorted, deterministic) ----------------
__global__ __launch_bounds__(256) void build_lists_kernel(
    const int* __restrict__ eidx,
    int* __restrict__ list,
    int* __restrict__ counts) {
    int e = blockIdx.x;          // 0..7
    int tid = threadIdx.x;       // 256
    int lane = tid & 63;
    int wv = tid >> 6;
    __shared__ int wsum[4];
    __shared__ int wbase[4];
    __shared__ int sbase;
    if (tid == 0) sbase = 0;
    __syncthreads();
    for (int c = 0; c < T_TOK; c += 256) {
        int tok = c + tid;
        int pk = eidx[tok];
        int slot = -1;
        if ((pk & 255) == e) slot = tok * 2;
        else if ((pk >> 8) == e) slot = tok * 2 + 1;
        unsigned long long m = __ballot(slot >= 0);
        int prefix = __popcll(m & ((1ull << lane) - 1ull));
        if (lane == 0) wsum[wv] = __popcll(m);
        __syncthreads();
        if (tid == 0) {
            int s = sbase;
#pragma unroll
            for (int i = 0; i < 4; ++i) { wbase[i] = s; s += wsum[i]; }
            sbase = s;
        }
        __syncthreads();
        if (slot >= 0) list[e * T_TOK + wbase[wv] + prefix] = slot;
        __syncthreads();
    }
    if (tid == 0) counts[e] = sbase;
}

// ---------------- GEMM 1&3 fused: act = silu(X w1^T) * (X w3^T) ----------------
__global__ __launch_bounds__(256, 2) void gemm13_kernel(
    const unsigned short* __restrict__ xb,
    const unsigned short* __restrict__ w1b,
    const unsigned short* __restrict__ w3b,
    const int* __restrict__ list,
    const int* __restrict__ counts,
    unsigned short* __restrict__ act) {
    int orig = blockIdx.x;
    int wg = (orig & 7) * 768 + (orig >> 3);
    int tm = wg & 31;
    int tn = (wg >> 5) % 24;
    int e = wg / (32 * 24);

    int cnt = counts[e];
    if (tm * 128 >= cnt) return;
    const int* lst = list + e * T_TOK + tm * 128;
    int mrem = cnt - tm * 128;

    __shared__ unsigned short sA[2][128 * 32];
    __shared__ unsigned short sB1[2][64 * 32];
    __shared__ unsigned short sB3[2][64 * 32];

    int tid = threadIdx.x;
    int lane = tid & 63;
    int wid = tid >> 6;

    int r0 = tid >> 2;
    int r1 = r0 + 64;
    int c8 = ((tid & 3) ^ (r0 & 3)) * 8;
    int tok0 = lst[(r0 < mrem) ? r0 : 0] >> 1;
    int tok1 = lst[(r1 < mrem) ? r1 : 0] >> 1;
    const unsigned short* gA0 = xb + (size_t)tok0 * H_DIM + c8;
    const unsigned short* gA1 = xb + (size_t)tok1 * H_DIM + c8;
    const unsigned short* gB1 = w1b + ((size_t)e * F_DIM + tn * 64 + r0) * H_DIM + c8;
    const unsigned short* gB3 = w3b + ((size_t)e * F_DIM + tn * 64 + r0) * H_DIM + c8;

    auto stage = [&](int b, int kt) {
        gload16(gA0 + kt, &sA[b][wid * 512]);
        gload16(gA1 + kt, &sA[b][2048 + wid * 512]);
        gload16(gB1 + kt, &sB1[b][wid * 512]);
        gload16(gB3 + kt, &sB3[b][wid * 512]);
    };

    int wr = (wid >> 1) * 64;
    int wc = (wid & 1) * 32;
    int fr = lane & 15;
    int kb = ((lane >> 4) ^ (lane & 3)) * 8;

    f32x4 accG[4][2] = {};
    f32x4 accU[4][2] = {};

    stage(0, 0);
    __syncthreads();
    int buf = 0;
    for (int kt = 0; kt < H_DIM; kt += 32) {
        if (kt + 32 < H_DIM) {
            stage(buf ^ 1, kt + 32);
            VMCNT(4);
        } else {
            VMCNT(0);
        }
        __builtin_amdgcn_s_barrier();
        CFENCE();

        bf16x8 a[4], b1[2], b3[2];
#pragma unroll
        for (int mi = 0; mi < 4; ++mi)
            a[mi] = *reinterpret_cast<const bf16x8*>(&sA[buf][(wr + mi * 16 + fr) * 32 + kb]);
#pragma unroll
        for (int ni = 0; ni < 2; ++ni) {
            b1[ni] = *reinterpret_cast<const bf16x8*>(&sB1[buf][(wc + ni * 16 + fr) * 32 + kb]);
            b3[ni] = *reinterpret_cast<const bf16x8*>(&sB3[buf][(wc + ni * 16 + fr) * 32 + kb]);
        }
#pragma unroll
        for (int mi = 0; mi < 4; ++mi)
#pragma unroll
            for (int ni = 0; ni < 2; ++ni) {
                accG[mi][ni] = __builtin_amdgcn_mfma_f32_16x16x32_bf16(a[mi], b1[ni], accG[mi][ni], 0, 0, 0);
                accU[mi][ni] = __builtin_amdgcn_mfma_f32_16x16x32_bf16(a[mi], b3[ni], accU[mi][ni], 0, 0, 0);
            }
        CFENCE();
        __builtin_amdgcn_s_barrier();
        buf ^= 1;
    }

    int rg = (lane >> 4) * 4;
    int ci = lane & 15;
#pragma unroll
    for (int mi = 0; mi < 4; ++mi) {
#pragma unroll
        for (int r = 0; r < 4; ++r) {
            int m = wr + mi * 16 + rg + r;
            if (m >= mrem) continue;
            int entry = lst[m];
            size_t rowOff = (size_t)entry * F_DIM + tn * 64;
#pragma unroll
            for (int ni = 0; ni < 2; ++ni) {
                float g = accG[mi][ni][r];
                float u = accU[mi][ni][r];
                float s = g / (1.f + __expf(-g));
                act[rowOff + wc + ni * 16 + ci] = f2bf(s * u);
            }
        }
    }
}

// ---------------- GEMM 2: ybuf = (act w2^T) * route_weight ----------------
__global__ __launch_bounds__(256, 2) void gemm2_kernel(
    const unsigned short* __restrict__ act,
    const unsigned short* __restrict__ w2b,
    const int* __restrict__ list,
    const int* __restrict__ counts,
    const float* __restrict__ weight,
    float* __restrict__ ybuf) {
    int orig = blockIdx.x;
    int wg = (orig & 7) * 384 + (orig >> 3);
    int tm = wg & 31;
    int tn = (wg >> 5) % 12;
    int e = wg / (32 * 12);

    int cnt = counts[e];
    if (tm * 128 >= cnt) return;
    const int* lst = list + e * T_TOK + tm * 128;
    int mrem = cnt - tm * 128;

    __shared__ unsigned short sA[2][128 * 32];
    __shared__ unsigned short sB[2][64 * 32];

    int tid = threadIdx.x;
    int lane = tid & 63;
    int wid = tid >> 6;

    int r0 = tid >> 2;
    int r1 = r0 + 64;
    int c8 = ((tid & 3) ^ (r0 & 3)) * 8;
    int row0 = lst[(r0 < mrem) ? r0 : 0];
    int row1 = lst[(r1 < mrem) ? r1 : 0];
    const unsigned short* gA0 = act + (size_t)row0 * F_DIM + c8;
    const unsigned short* gA1 = act + (size_t)row1 * F_DIM + c8;
    const unsigned short* gB = w2b + ((size_t)e * H_DIM + tn * 64 + r0) * F_DIM + c8;

    auto stage = [&](int b, int kt) {
        gload16(gA0 + kt, &sA[b][wid * 512]);
        gload16(gA1 + kt, &sA[b][2048 + wid * 512]);
        gload16(gB + kt, &sB[b][wid * 512]);
    };

    int wr = (wid >> 1) * 64;
    int wc = (wid & 1) * 32;
    int fr = lane & 15;
    int kb = ((lane >> 4) ^ (lane & 3)) * 8;

    f32x4 acc[4][2] = {};

    stage(0, 0);
    __syncthreads();
    int buf = 0;
    for (int kt = 0; kt < F_DIM; kt += 32) {
        if (kt + 32 < F_DIM) {
            stage(buf ^ 1, kt + 32);
            VMCNT(3);
        } else {
            VMCNT(0);
        }
        __builtin_amdgcn_s_barrier();
        CFENCE();

        bf16x8 a[4], b[2];
#pragma unroll
        for (int mi = 0; mi < 4; ++mi)
            a[mi] = *reinterpret_cast<const bf16x8*>(&sA[buf][(wr + mi * 16 + fr) * 32 + kb]);
#pragma unroll
        for (int ni = 0; ni < 2; ++ni)
            b[ni] = *reinterpret_cast<const bf16x8*>(&sB[buf][(wc + ni * 16 + fr) * 32 + kb]);
#pragma unroll
        for (int mi = 0; mi < 4; ++mi)
#pragma unroll
            for (int ni = 0; ni < 2; ++ni)
                acc[mi][ni] = __builtin_amdgcn_mfma_f32_16x16x32_bf16(a[mi], b[ni], acc[mi][ni], 0, 0, 0);
        CFENCE();
        __builtin_amdgcn_s_barrier();
        buf ^= 1;
    }

    int rg = (lane >> 4) * 4;
    int ci = lane & 15;
#pragma unroll
    for (int mi = 0; mi < 4; ++mi) {
#pragma unroll
        for (int r = 0; r < 4; ++r) {
            int m = wr + mi * 16 + rg + r;
            if (m >= mrem) continue;
            int entry = lst[m];
            float wv = weight[entry];
            size_t rowOff = (size_t)entry * H_DIM + tn * 64;
#pragma unroll
            for (int ni = 0; ni < 2; ++ni)
                ybuf[rowOff + wc + ni * 16 + ci] = acc[mi][ni][r] * wv;
        }
    }
}

// ---------------- combine: y[t] = ybuf[2t] + ybuf[2t+1] ----------------
__global__ void combine_kernel(const float* __restrict__ ybuf, float* __restrict__ y) {
    int v = blockIdx.x * blockDim.x + threadIdx.x;
    if (v >= T_TOK * H_DIM / 4) return;
    int t = v / (H_DIM / 4);
    int hv = v % (H_DIM / 4);
    float4 a = reinterpret_cast<const float4*>(ybuf + (size_t)(2 * t) * H_DIM)[hv];
    float4 b = reinterpret_cast<const float4*>(ybuf + (size_t)(2 * t + 1) * H_DIM)[hv];
    float4 r;
    r.x = a.x + b.x; r.y = a.y + b.y; r.z = a.z + b.z; r.w = a.w + b.w;
    reinterpret_cast<float4*>(y)[v] = r;
}

extern "C" void kernel_launch(void* const* d_in, const int* in_sizes, int n_in,
                              void* d_out, int out_size, void* d_ws, size_t ws_size,
                              hipStream_t stream) {
    const float* x  = (const float*)d_in[0];
    const float* gw = (const float*)d_in[1];
    const float* w1 = (const float*)d_in[2];
    const float* w3 = (const float*)d_in[3];
    const float* w2 = (const float*)d_in[4];

    float* y = (float*)d_out;
    float* logits_out = y + (size_t)T_TOK * H_DIM;

    char* ws = (char*)d_ws;
    size_t off = 0;
    auto alloc = [&](size_t bytes) -> char* {
        char* p = ws + off;
        off += (bytes + 255) & ~(size_t)255;
        return p;
    };
    unsigned short* xb  = (unsigned short*)alloc((size_t)T_TOK * H_DIM * 2);
    unsigned short* w1b = (unsigned short*)alloc((size_t)E_NUM * F_DIM * H_DIM * 2);
    unsigned short* w3b = (unsigned short*)alloc((size_t)E_NUM * F_DIM * H_DIM * 2);
    unsigned short* w2b = (unsigned short*)alloc((size_t)E_NUM * H_DIM * F_DIM * 2);
    unsigned short* act = (unsigned short*)alloc((size_t)T_TOK * 2 * F_DIM * 2);
    float* ybuf   = (float*)alloc((size_t)T_TOK * 2 * H_DIM * 4);
    float* weight = (float*)alloc((size_t)T_TOK * 2 * 4);
    int* list     = (int*)alloc((size_t)E_NUM * T_TOK * 4);
    int* counts   = (int*)alloc((size_t)E_NUM * 4);
    int* eidx     = (int*)alloc((size_t)T_TOK * 4);

    convert_bf16_kernel<<<2048, 256, 0, stream>>>(w1, w1b, E_NUM * F_DIM * H_DIM);
    convert_bf16_kernel<<<2048, 256, 0, stream>>>(w3, w3b, E_NUM * F_DIM * H_DIM);
    convert_bf16_kernel<<<2048, 256, 0, stream>>>(w2, w2b, E_NUM * H_DIM * F_DIM);

    router_kernel<<<T_TOK / 4, 256, 0, stream>>>(x, gw, logits_out, weight, eidx, xb);

    build_lists_kernel<<<E_NUM, 256, 0, stream>>>(eidx, list, counts);

    gemm13_kernel<<<6144, 256, 0, stream>>>(xb, w1b, w3b, list, counts, act);

    gemm2_kernel<<<3072, 256, 0, stream>>>(act, w2b, list, counts, weight, ybuf);

    combine_kernel<<<(T_TOK * H_DIM / 4 + 255) / 256, 256, 0, stream>>>(ybuf, y);
}

// Round 6
// 175.848 us; speedup vs baseline: 3.2080x; 1.0029x over previous
//
#include <hip/hip_runtime.h>
#include <hip/hip_bf16.h>

#define T_TOK 4096
#define H_DIM 768
#define E_NUM 8
#define F_DIM 1536

typedef __bf16 bf16x8 __attribute__((ext_vector_type(8)));
typedef float f32x4 __attribute__((ext_vector_type(4)));
typedef unsigned int u32;

#define VMCNT(n) asm volatile("s_waitcnt vmcnt(" #n ")" ::: "memory")
#define CFENCE() asm volatile("" ::: "memory")

__device__ __forceinline__ unsigned short f2bf(float f) {
    unsigned int u = __float_as_uint(f);
    u += 0x7FFF + ((u >> 16) & 1);   // RNE
    return (unsigned short)(u >> 16);
}

// async global(16B/lane) -> LDS (wave-uniform base + lane*16)
__device__ __forceinline__ void gload16(const unsigned short* g, unsigned short* l) {
    __builtin_amdgcn_global_load_lds(
        (const __attribute__((address_space(1))) u32*)(g),
        (__attribute__((address_space(3))) u32*)(l),
        16, 0, 0);
}

// ---------------- fp32 -> bf16 convert (weights) ----------------
__global__ void convert_bf16_kernel(const float* __restrict__ src,
                                    unsigned short* __restrict__ dst, int n) {
    int i = (blockIdx.x * blockDim.x + threadIdx.x) * 4;
    int stride = gridDim.x * blockDim.x * 4;
    for (; i < n; i += stride) {
        float4 v = *reinterpret_cast<const float4*>(src + i);
        ushort4 o;
        o.x = f2bf(v.x); o.y = f2bf(v.y); o.z = f2bf(v.z); o.w = f2bf(v.w);
        *reinterpret_cast<ushort4*>(dst + i) = o;
    }
}

// ---------------- router: logits + top2 + x->bf16, NO atomics ----------------
__global__ __launch_bounds__(256) void router_kernel(
    const float* __restrict__ x,
    const float* __restrict__ gw,
    float* __restrict__ logits_out,
    float* __restrict__ weight,
    int* __restrict__ eidx,
    unsigned short* __restrict__ xb) {
    int t = blockIdx.x * 4 + (threadIdx.x >> 6);
    int lane = threadIdx.x & 63;

    const float4* xr = reinterpret_cast<const float4*>(x + (size_t)t * H_DIM);
    float4 xv[3];
#pragma unroll
    for (int i = 0; i < 3; ++i) xv[i] = xr[i * 64 + lane];

    unsigned short* xbr = xb + (size_t)t * H_DIM;
#pragma unroll
    for (int i = 0; i < 3; ++i) {
        ushort4 o;
        o.x = f2bf(xv[i].x); o.y = f2bf(xv[i].y);
        o.z = f2bf(xv[i].z); o.w = f2bf(xv[i].w);
        *reinterpret_cast<ushort4*>(xbr + (i * 64 + lane) * 4) = o;
    }

    float v[E_NUM];
#pragma unroll
    for (int e = 0; e < E_NUM; ++e) {
        const float4* g = reinterpret_cast<const float4*>(gw + e * H_DIM);
        float p = 0.f;
#pragma unroll
        for (int i = 0; i < 3; ++i) {
            float4 gv = g[i * 64 + lane];
            p += xv[i].x * gv.x + xv[i].y * gv.y + xv[i].z * gv.z + xv[i].w * gv.w;
        }
        v[e] = p;
    }
#pragma unroll
    for (int d = 1; d < 8; d <<= 1)
#pragma unroll
        for (int e = 0; e < E_NUM; ++e) v[e] += __shfl_xor(v[e], d);
    int me = lane & 7;
    float le = v[0];
#pragma unroll
    for (int e = 1; e < E_NUM; ++e) le = (me == e) ? v[e] : le;
#pragma unroll
    for (int d = 8; d < 64; d <<= 1) le += __shfl_xor(le, d);

    if (lane < 8) logits_out[t * E_NUM + lane] = le;

    float m0 = le;
#pragma unroll
    for (int d = 1; d < 8; d <<= 1) m0 = fmaxf(m0, __shfl_xor(m0, d));
    unsigned long long b0 = __ballot(le == m0);
    int e0 = (__ffsll((long long)b0) - 1) & 7;
    float le1 = (me == e0) ? -3.4e38f : le;
    float m1 = le1;
#pragma unroll
    for (int d = 1; d < 8; d <<= 1) m1 = fmaxf(m1, __shfl_xor(m1, d));
    unsigned long long b1 = __ballot(le1 == m1);
    int e1 = (__ffsll((long long)b1) - 1) & 7;

    if (lane == 0) {
        float w0 = 1.f / (1.f + __expf(m1 - m0));
        weight[t * 2 + 0] = w0;
        weight[t * 2 + 1] = 1.f - w0;
        eidx[t] = e0 | (e1 << 8);
    }
}

// ---------------- build per-expert token lists (sorted, deterministic) ----------------
__global__ __launch_bounds__(256) void build_lists_kernel(
    const int* __restrict__ eidx,
    int* __restrict__ list,
    int* __restrict__ counts) {
    int e = blockIdx.x;
    int tid = threadIdx.x;
    int lane = tid & 63;
    int wv = tid >> 6;
    __shared__ int wsum[4];
    __shared__ int wbase[4];
    __shared__ int sbase;
    if (tid == 0) sbase = 0;
    __syncthreads();
    for (int c = 0; c < T_TOK; c += 256) {
        int tok = c + tid;
        int pk = eidx[tok];
        int slot = -1;
        if ((pk & 255) == e) slot = tok * 2;
        else if ((pk >> 8) == e) slot = tok * 2 + 1;
        unsigned long long m = __ballot(slot >= 0);
        int prefix = __popcll(m & ((1ull << lane) - 1ull));
        if (lane == 0) wsum[wv] = __popcll(m);
        __syncthreads();
        if (tid == 0) {
            int s = sbase;
#pragma unroll
            for (int i = 0; i < 4; ++i) { wbase[i] = s; s += wsum[i]; }
            sbase = s;
        }
        __syncthreads();
        if (slot >= 0) list[e * T_TOK + wbase[wv] + prefix] = slot;
        __syncthreads();
    }
    if (tid == 0) counts[e] = sbase;
}

// ---------------- GEMM 1&3 fused: act = silu(X w1^T) * (X w3^T) ----------------
__global__ __launch_bounds__(256, 3) void gemm13_kernel(
    const unsigned short* __restrict__ xb,
    const unsigned short* __restrict__ w1b,
    const unsigned short* __restrict__ w3b,
    const int* __restrict__ list,
    const int* __restrict__ counts,
    unsigned short* __restrict__ act) {
    int orig = blockIdx.x;
    int wg = (orig & 7) * 768 + (orig >> 3);
    int tm = wg & 31;
    int tn = (wg >> 5) % 24;
    int e = wg / (32 * 24);

    int cnt = counts[e];
    if (tm * 128 >= cnt) return;
    const int* lst = list + e * T_TOK + tm * 128;
    int mrem = cnt - tm * 128;

    __shared__ unsigned short sA[2][128 * 32];
    __shared__ unsigned short sB1[2][64 * 32];
    __shared__ unsigned short sB3[2][64 * 32];

    int tid = threadIdx.x;
    int lane = tid & 63;
    int wid = tid >> 6;

    int r0 = tid >> 2;
    int r1 = r0 + 64;
    int c8 = ((tid & 3) ^ ((r0 >> 1) & 3)) * 8;   // bank-correct pre-swizzle
    int tok0 = lst[(r0 < mrem) ? r0 : 0] >> 1;
    int tok1 = lst[(r1 < mrem) ? r1 : 0] >> 1;
    const unsigned short* gA0 = xb + (size_t)tok0 * H_DIM + c8;
    const unsigned short* gA1 = xb + (size_t)tok1 * H_DIM + c8;
    const unsigned short* gB1 = w1b + ((size_t)e * F_DIM + tn * 64 + r0) * H_DIM + c8;
    const unsigned short* gB3 = w3b + ((size_t)e * F_DIM + tn * 64 + r0) * H_DIM + c8;

    auto stage = [&](int b, int kt) {
        gload16(gA0 + kt, &sA[b][wid * 512]);
        gload16(gA1 + kt, &sA[b][2048 + wid * 512]);
        gload16(gB1 + kt, &sB1[b][wid * 512]);
        gload16(gB3 + kt, &sB3[b][wid * 512]);
    };

    int wr = (wid >> 1) * 64;
    int wc = (wid & 1) * 32;
    int fr = lane & 15;
    int kb = ((lane >> 4) ^ ((lane >> 1) & 3)) * 8;  // matching read XOR

    f32x4 accG[4][2] = {};
    f32x4 accU[4][2] = {};

    stage(0, 0);
    __syncthreads();
    int buf = 0;
    for (int kt = 0; kt < H_DIM; kt += 32) {
        if (kt + 32 < H_DIM) {
            stage(buf ^ 1, kt + 32);
            VMCNT(4);
        } else {
            VMCNT(0);
        }
        __builtin_amdgcn_s_barrier();
        CFENCE();

        bf16x8 a[4], b1[2], b3[2];
#pragma unroll
        for (int mi = 0; mi < 4; ++mi)
            a[mi] = *reinterpret_cast<const bf16x8*>(&sA[buf][(wr + mi * 16 + fr) * 32 + kb]);
#pragma unroll
        for (int ni = 0; ni < 2; ++ni) {
            b1[ni] = *reinterpret_cast<const bf16x8*>(&sB1[buf][(wc + ni * 16 + fr) * 32 + kb]);
            b3[ni] = *reinterpret_cast<const bf16x8*>(&sB3[buf][(wc + ni * 16 + fr) * 32 + kb]);
        }
#pragma unroll
        for (int mi = 0; mi < 4; ++mi)
#pragma unroll
            for (int ni = 0; ni < 2; ++ni) {
                accG[mi][ni] = __builtin_amdgcn_mfma_f32_16x16x32_bf16(a[mi], b1[ni], accG[mi][ni], 0, 0, 0);
                accU[mi][ni] = __builtin_amdgcn_mfma_f32_16x16x32_bf16(a[mi], b3[ni], accU[mi][ni], 0, 0, 0);
            }
        CFENCE();
        __builtin_amdgcn_s_barrier();
        buf ^= 1;
    }

    int rg = (lane >> 4) * 4;
    int ci = lane & 15;
#pragma unroll
    for (int mi = 0; mi < 4; ++mi) {
#pragma unroll
        for (int r = 0; r < 4; ++r) {
            int m = wr + mi * 16 + rg + r;
            if (m >= mrem) continue;
            int entry = lst[m];
            size_t rowOff = (size_t)entry * F_DIM + tn * 64;
#pragma unroll
            for (int ni = 0; ni < 2; ++ni) {
                float g = accG[mi][ni][r];
                float u = accU[mi][ni][r];
                float s = g / (1.f + __expf(-g));
                act[rowOff + wc + ni * 16 + ci] = f2bf(s * u);
            }
        }
    }
}

// ---------------- GEMM 2: ybuf = (act w2^T) * route_weight ----------------
__global__ __launch_bounds__(256, 4) void gemm2_kernel(
    const unsigned short* __restrict__ act,
    const unsigned short* __restrict__ w2b,
    const int* __restrict__ list,
    const int* __restrict__ counts,
    const float* __restrict__ weight,
    float* __restrict__ ybuf) {
    int orig = blockIdx.x;
    int wg = (orig & 7) * 384 + (orig >> 3);
    int tm = wg & 31;
    int tn = (wg >> 5) % 12;
    int e = wg / (32 * 12);

    int cnt = counts[e];
    if (tm * 128 >= cnt) return;
    const int* lst = list + e * T_TOK + tm * 128;
    int mrem = cnt - tm * 128;

    __shared__ unsigned short sA[2][128 * 32];
    __shared__ unsigned short sB[2][64 * 32];

    int tid = threadIdx.x;
    int lane = tid & 63;
    int wid = tid >> 6;

    int r0 = tid >> 2;
    int r1 = r0 + 64;
    int c8 = ((tid & 3) ^ ((r0 >> 1) & 3)) * 8;
    int row0 = lst[(r0 < mrem) ? r0 : 0];
    int row1 = lst[(r1 < mrem) ? r1 : 0];
    const unsigned short* gA0 = act + (size_t)row0 * F_DIM + c8;
    const unsigned short* gA1 = act + (size_t)row1 * F_DIM + c8;
    const unsigned short* gB = w2b + ((size_t)e * H_DIM + tn * 64 + r0) * F_DIM + c8;

    auto stage = [&](int b, int kt) {
        gload16(gA0 + kt, &sA[b][wid * 512]);
        gload16(gA1 + kt, &sA[b][2048 + wid * 512]);
        gload16(gB + kt, &sB[b][wid * 512]);
    };

    int wr = (wid >> 1) * 64;
    int wc = (wid & 1) * 32;
    int fr = lane & 15;
    int kb = ((lane >> 4) ^ ((lane >> 1) & 3)) * 8;

    f32x4 acc[4][2] = {};

    stage(0, 0);
    __syncthreads();
    int buf = 0;
    for (int kt = 0; kt < F_DIM; kt += 32) {
        if (kt + 32 < F_DIM) {
            stage(buf ^ 1, kt + 32);
            VMCNT(3);
        } else {
            VMCNT(0);
        }
        __builtin_amdgcn_s_barrier();
        CFENCE();

        bf16x8 a[4], b[2];
#pragma unroll
        for (int mi = 0; mi < 4; ++mi)
            a[mi] = *reinterpret_cast<const bf16x8*>(&sA[buf][(wr + mi * 16 + fr) * 32 + kb]);
#pragma unroll
        for (int ni = 0; ni < 2; ++ni)
            b[ni] = *reinterpret_cast<const bf16x8*>(&sB[buf][(wc + ni * 16 + fr) * 32 + kb]);
#pragma unroll
        for (int mi = 0; mi < 4; ++mi)
#pragma unroll
            for (int ni = 0; ni < 2; ++ni)
                acc[mi][ni] = __builtin_amdgcn_mfma_f32_16x16x32_bf16(a[mi], b[ni], acc[mi][ni], 0, 0, 0);
        CFENCE();
        __builtin_amdgcn_s_barrier();
        buf ^= 1;
    }

    int rg = (lane >> 4) * 4;
    int ci = lane & 15;
#pragma unroll
    for (int mi = 0; mi < 4; ++mi) {
#pragma unroll
        for (int r = 0; r < 4; ++r) {
            int m = wr + mi * 16 + rg + r;
            if (m >= mrem) continue;
            int entry = lst[m];
            float wv = weight[entry];
            size_t rowOff = (size_t)entry * H_DIM + tn * 64;
#pragma unroll
            for (int ni = 0; ni < 2; ++ni)
                ybuf[rowOff + wc + ni * 16 + ci] = acc[mi][ni][r] * wv;
        }
    }
}

// ---------------- combine: y[t] = ybuf[2t] + ybuf[2t+1] ----------------
__global__ void combine_kernel(const float* __restrict__ ybuf, float* __restrict__ y) {
    int v = blockIdx.x * blockDim.x + threadIdx.x;
    if (v >= T_TOK * H_DIM / 4) return;
    int t = v / (H_DIM / 4);
    int hv = v % (H_DIM / 4);
    float4 a = reinterpret_cast<const float4*>(ybuf + (size_t)(2 * t) * H_DIM)[hv];
    float4 b = reinterpret_cast<const float4*>(ybuf + (size_t)(2 * t + 1) * H_DIM)[hv];
    float4 r;
    r.x = a.x + b.x; r.y = a.y + b.y; r.z = a.z + b.z; r.w = a.w + b.w;
    reinterpret_cast<float4*>(y)[v] = r;
}

extern "C" void kernel_launch(void* const* d_in, const int* in_sizes, int n_in,
                              void* d_out, int out_size, void* d_ws, size_t ws_size,
                              hipStream_t stream) {
    const float* x  = (const float*)d_in[0];
    const float* gw = (const float*)d_in[1];
    const float* w1 = (const float*)d_in[2];
    const float* w3 = (const float*)d_in[3];
    const float* w2 = (const float*)d_in[4];

    float* y = (float*)d_out;
    float* logits_out = y + (size_t)T_TOK * H_DIM;

    char* ws = (char*)d_ws;
    size_t off = 0;
    auto alloc = [&](size_t bytes) -> char* {
        char* p = ws + off;
        off += (bytes + 255) & ~(size_t)255;
        return p;
    };
    unsigned short* xb  = (unsigned short*)alloc((size_t)T_TOK * H_DIM * 2);
    unsigned short* w1b = (unsigned short*)alloc((size_t)E_NUM * F_DIM * H_DIM * 2);
    unsigned short* w3b = (unsigned short*)alloc((size_t)E_NUM * F_DIM * H_DIM * 2);
    unsigned short* w2b = (unsigned short*)alloc((size_t)E_NUM * H_DIM * F_DIM * 2);
    unsigned short* act = (unsigned short*)alloc((size_t)T_TOK * 2 * F_DIM * 2);
    float* ybuf   = (float*)alloc((size_t)T_TOK * 2 * H_DIM * 4);
    float* weight = (float*)alloc((size_t)T_TOK * 2 * 4);
    int* list     = (int*)alloc((size_t)E_NUM * T_TOK * 4);
    int* counts   = (int*)alloc((size_t)E_NUM * 4);
    int* eidx     = (int*)alloc((size_t)T_TOK * 4);

    convert_bf16_kernel<<<2048, 256, 0, stream>>>(w1, w1b, E_NUM * F_DIM * H_DIM);
    convert_bf16_kernel<<<2048, 256, 0, stream>>>(w3, w3b, E_NUM * F_DIM * H_DIM);
    convert_bf16_kernel<<<2048, 256, 0, stream>>>(w2, w2b, E_NUM * H_DIM * F_DIM);

    router_kernel<<<T_TOK / 4, 256, 0, stream>>>(x, gw, logits_out, weight, eidx, xb);

    build_lists_kernel<<<E_NUM, 256, 0, stream>>>(eidx, list, counts);

    gemm13_kernel<<<6144, 256, 0, stream>>>(xb, w1b, w3b, list, counts, act);

    gemm2_kernel<<<3072, 256, 0, stream>>>(act, w2b, list, counts, weight, ybuf);

    combine_kernel<<<(T_TOK * H_DIM / 4 + 255) / 256, 256, 0, stream>>>(ybuf, y);
}